// Round 14
// baseline (107.430 us; speedup 1.0000x reference)
//
#include <hip/hip_runtime.h>
#include <math.h>

namespace {

typedef unsigned short u16;
typedef short bf16x8 __attribute__((ext_vector_type(8)));
typedef float f32x4 __attribute__((ext_vector_type(4)));
typedef unsigned short u16x4 __attribute__((ext_vector_type(4)));
typedef unsigned short u16x2 __attribute__((ext_vector_type(2)));
typedef unsigned long long u64;

constexpr int NPTS = 8192;
constexpr int KNB  = 16;

// padded bf16 weight-copy layout (u16 offsets; all row strides 16B multiples)
constexpr int OFF_W0   = 0;       // [128][200] = 25600
constexpr int OFF_PH2  = 25600;   // phase-2 contiguous block:
constexpr int P2_WM1   = 0;       //   [48][200] = 9600   (mix_in dims 0..169)
constexpr int P2_WM1E  = 9600;    //   [48][136] = 6528   (feat_s dims 170..297)
constexpr int P2_W1A   = 16128;   //   [64][72]  = 4608
constexpr int P2_W1C   = 20736;   //   [64][72]  = 4608
constexpr int PH2_SZ   = 25344;
constexpr int OFF_W1B  = 50944;   // [64][136] = 8704
constexpr int OFF_WM2  = 59648;   // [192][72] = 13824
constexpr int WCOPY    = 73472;   // u16 per copy (146944 B)
constexpr int NCOPY    = 8;

__device__ __forceinline__ u16 f2bf(float f) {           // round-half-up, 2 ops
  return (u16)((__float_as_uint(f) + 0x8000u) >> 16);
}
// pack 2 floats -> 2 bf16 in one dword: (hi=b, lo=a); 3 VALU ops
__device__ __forceinline__ unsigned int pk2bf(float a, float b) {
  const unsigned int ua = __float_as_uint(a) + 0x8000u;
  const unsigned int ub = __float_as_uint(b) + 0x8000u;
  return __builtin_amdgcn_perm(ub, ua, 0x07060302);
}

__device__ __forceinline__ void wave_argmin(float& best, int& bj) {
#pragma unroll
  for (int off = 32; off; off >>= 1) {
    float ob = __shfl_xor(best, off);
    int   oj = __shfl_xor(bj, off);
    if (ob < best || (ob == best && oj < bj)) { best = ob; bj = oj; }
  }
}

// ---------------- setup: prep (0..287) + interior KNN quarters (288..2335) + edge (2336..2351) ----------------
// Interior KNN writes packed4[pp*4+q] with a PLAIN store (each (point,quarter)
// pair owned by exactly one wave) -> no init, no atomics. u64 order preserves
// exact (d2, lower-j) lexicographic tie-break.
__global__ __launch_bounds__(256) void setup_all(
    const float* __restrict__ coord,
    const float* __restrict__ W0, const float* __restrict__ W1,
    const float* __restrict__ w1, const float* __restrict__ w2,
    u16* __restrict__ Wrep, float* __restrict__ w0last, float* __restrict__ w1last,
    int* __restrict__ nei, u64* __restrict__ packed4) {
  const int b = blockIdx.x;
  if (b < 288) {
    const int t = b * 256 + threadIdx.x;
    if (t < WCOPY) {
      u16 val = 0;
      int i = t;
      if (i < 25600)                 { const int d = i/200, c = i%200; if (c < 192) val = f2bf(W0[c*128 + d]); }
      else if ((i -= 25600) < 9600)  { const int r = i/200, c = i%200; if (r < 42 && c < 170) val = f2bf(w1[c*42 + r]); }
      else if ((i -= 9600)  < 6528)  { const int r = i/136, c = i%136; if (r < 42 && c < 128) val = f2bf(w1[(170+c)*42 + r]); }
      else if ((i -= 6528)  < 4608)  { const int d = i/72,  c = i%72;  if (c < 64)  val = f2bf(W1[c*64 + d]); }
      else if ((i -= 4608)  < 4608)  { const int d = i/72,  c = i%72;  if (c < 64)  val = f2bf(W1[(192+c)*64 + d]); }
      else if ((i -= 4608)  < 8704)  { const int d = i/136, c = i%136; if (c < 128) val = f2bf(W1[(64+c)*64 + d]); }
      else { i -= 8704;                const int e = i/72,  rr = i%72; if (rr < 42) val = f2bf(w2[rr*192 + e]); }
#pragma unroll
      for (int cp = 0; cp < NCOPY; ++cp) Wrep[cp*WCOPY + t] = val;
      return;
    }
    int t2 = t - WCOPY;
    if (t2 < 128) { w0last[t2] = W0[192*128 + t2]; return; }
    t2 -= 128;
    if (t2 < 64)  { w1last[t2] = W1[256*64 + t2]; return; }
    return;
  }
  if (b < 2336) {
    const int qb = b - 288;
    const int g  = qb >> 2;          // 0..511
    const int q  = qb & 3;           // range quarter
    const int lane = threadIdx.x & 63;
    const int wid  = g * 4 + (threadIdx.x >> 6);
    int p[4]; float cx[4], cy[4], cz[4], best[4]; int bj[4];
#pragma unroll
    for (int t = 0; t < 4; ++t) {
      p[t] = wid + 2048 * t;
      cx[t] = coord[3*p[t]+0]; cy[t] = coord[3*p[t]+1]; cz[t] = coord[3*p[t]+2];
      best[t] = 3.0e38f; bj[t] = NPTS;
    }
    const int j0 = q * 2048;
    for (int j = j0 + lane; j < j0 + 2048; j += 64) {
      const float x = coord[3*j+0], y = coord[3*j+1], z = coord[3*j+2];
#pragma unroll
      for (int t = 0; t < 4; ++t) {
        int dd = j - p[t]; dd = dd < 0 ? -dd : dd;
        const float dx = x-cx[t], dy = y-cy[t], dz = z-cz[t];
        const float d2 = dx*dx + dy*dy + dz*dz;
        if (dd > 8 && d2 < best[t]) { best[t] = d2; bj[t] = j; }
      }
    }
#pragma unroll
    for (int t = 0; t < 4; ++t) {
      wave_argmin(best[t], bj[t]);
      const int pp = p[t];
      if (lane == 0 && pp >= 8 && pp < NPTS-8)
        packed4[pp*4 + q] = ((u64)__float_as_uint(best[t]) << 32) | (unsigned)bj[t];
    }
    return;
  }
  // edge KNN: 1 block per edge point (16 blocks) -> nei table rows
  {
    const int eb = b - 2336;
    const int n = (eb < 8) ? eb : (NPTS - 16 + eb);
    const int tid = threadIdx.x;
    const int lane = tid & 63;
    const int wv = tid >> 6;
    __shared__ float l_best[4];
    __shared__ int   l_bj[4];
    __shared__ int   l_sel;
    __shared__ int   s_sel[9];
    const float cx = coord[3*n+0], cy = coord[3*n+1], cz = coord[3*n+2];
    float d2v[32];
    unsigned int alive = 0;
#pragma unroll
    for (int q = 0; q < 32; ++q) {
      const int j = tid + q * 256;
      int dd = j - n; dd = dd < 0 ? -dd : dd;
      const float dx = coord[3*j+0]-cx, dy = coord[3*j+1]-cy, dz = coord[3*j+2]-cz;
      d2v[q] = dx*dx + dy*dy + dz*dz;
      if (dd > 8) alive |= (1u << q);
    }
    const int lo = (n-8 < 0) ? 0 : n-8;
    const int hi = (n+8 > NPTS-1) ? NPTS-1 : n+8;
    const int s  = (KNB + 1) - (hi - lo);
    for (int p = 0; p < s; ++p) {
      float best = 3.0e38f; int bj = NPTS;
#pragma unroll
      for (int q = 0; q < 32; ++q) {
        if ((alive >> q) & 1u) {
          const int j = tid + q * 256;
          if (d2v[q] < best) { best = d2v[q]; bj = j; }
        }
      }
      wave_argmin(best, bj);
      if (lane == 0) { l_best[wv] = best; l_bj[wv] = bj; }
      __syncthreads();
      if (tid == 0) {
        float bb = l_best[0]; int jj = l_bj[0];
        for (int w2 = 1; w2 < 4; ++w2)
          if (l_best[w2] < bb || (l_best[w2] == bb && l_bj[w2] < jj)) { bb = l_best[w2]; jj = l_bj[w2]; }
        l_sel = jj; s_sel[p] = jj;
      }
      __syncthreads();
      const int dq = l_sel - tid;
      if (dq >= 0 && (dq & 255) == 0) alive &= ~(1u << (dq >> 8));
      __syncthreads();
    }
    if (tid == 0) {
      const int first = (lo == n) ? (lo + 1) : lo;
      int idx = 0;
      for (int j = lo; j <= hi; ++j) {
        if (j == n || j == first) continue;
        nei[n*KNB + (idx++)] = j;
      }
      for (int p = 0; p < s; ++p) nei[n*KNB + (idx++)] = s_sel[p];
    }
  }
}

// async block-cooperative staging: global -> LDS direct. 512 threads x 16B.
__device__ __forceinline__ void stage(u16* dst, const u16* src, int n, int t) {
  for (int i = t*8; i < n; i += 4096)
    __builtin_amdgcn_global_load_lds(
        (const __attribute__((address_space(1))) unsigned int*)(src + i),
        (__attribute__((address_space(3))) unsigned int*)(dst + i), 16, 0, 0);
}

// ---------------- fused MFMA conv: 16 pts/block = 8 waves x 2 pts, shared B-frags ----------------
#define LFRAG(BUF, ldk, cb, kb) (*(const bf16x8*)&(BUF)[((cb)*16 + colb)*(ldk) + (kb)*32 + rowg*8])

__global__ __launch_bounds__(512, 2) void conv_mfma(
    const float* __restrict__ coord,
    const float* __restrict__ feat_s,
    const float* __restrict__ feat_v,
    const int*   __restrict__ nei,
    const u64*   __restrict__ packed4,
    const u16*   __restrict__ Wrep,
    const float* __restrict__ w0last,
    const float* __restrict__ w1last,
    const float* __restrict__ b1,
    const float* __restrict__ b2,
    const float* __restrict__ w_move,
    float* __restrict__ out) {

  __shared__ __align__(16) u16 wbuf[25600];   // W0 -> {WM1, WM1E, W1A, W1C}
  __shared__ __align__(16) u16 wbuf2[13824];  // W1B -> WM2
  __shared__ __align__(16) u16 bA[16][16][136];
  __shared__ float s_vec[16][16][4];
  __shared__ int   s_nei[16][16];

  const int t = threadIdx.x;
  const int w = t >> 6;
  const int l = t & 63;
  const int colb = l & 15;
  const int rowg = l >> 4;
  const int nb = blockIdx.x * 16;
  const int p0 = nb + 2*w;     // wave's two points: p0, p0+1
  const u16* Wc = Wrep + (blockIdx.x & 7) * WCOPY;

  constexpr float RS193 = 0.07198158f;
  constexpr float RS257 = 0.06237829f;
  constexpr float RS298 = 0.05792841f;
  constexpr float RS42  = 0.15430335f;
  constexpr float IS2   = 0.70710678f;
  constexpr float SQ3   = 1.73205081f;
  constexpr float RINV  = 0.21693046f;

  // ---- async stage of phase-1 weights ----
  stage(wbuf,  Wc + OFF_W0,  25600, t);
  stage(wbuf2, Wc + OFF_W1B, 8704,  t);

  union U8 { unsigned int d[4]; u16 u[8]; bf16x8 v; };
  bf16x8 aS[2][4], aT[2][2];

  // ---- gather (wave-local; overlaps staging latency) ----
#pragma unroll
  for (int m = 0; m < 2; ++m) {
    const int pt = 2*w + m;
    const int pm = p0 + m;
    if (l < 16) {
      int j;
      const bool is_edge = (pm < 8) || (pm >= NPTS-8);
      if (is_edge) {
        j = nei[pm*KNB + l];
      } else if (l < 15) {
        j = pm - 7 + l + (l >= 7 ? 1 : 0);          // band neighbor (analytic)
      } else {
        const u64* pp4 = packed4 + pm*4;            // min of 4 quarter-candidates
        u64 q0 = pp4[0], q1 = pp4[1], q2 = pp4[2], q3 = pp4[3];
        u64 mn = q0 < q1 ? q0 : q1;
        u64 mn2 = q2 < q3 ? q2 : q3;
        mn = mn < mn2 ? mn : mn2;
        j = (int)(unsigned)(mn & 0xFFFFFFFFull);
      }
      s_nei[pt][l] = j;
      const float v0 = coord[3*j+0] - coord[3*pm+0];
      const float v1 = coord[3*j+1] - coord[3*pm+1];
      const float v2 = coord[3*j+2] - coord[3*pm+2];
      const float n2 = v0*v0 + v1*v1 + v2*v2;
      s_vec[pt][l][0] = v0; s_vec[pt][l][1] = v1; s_vec[pt][l][2] = v2;
      s_vec[pt][l][3] = sqrtf(n2 == 0.0f ? 1.0f : n2);
    }
    const int jn = s_nei[pt][colb];
    const float v0 = s_vec[pt][colb][0], v1 = s_vec[pt][colb][1], v2 = s_vec[pt][colb][2];
    const float* fsp = feat_s + jn*128 + rowg*8;
#pragma unroll
    for (int kb = 0; kb < 4; ++kb) {
      const float4 a = *(const float4*)(fsp + kb*32);
      const float4 b = *(const float4*)(fsp + kb*32 + 4);
      U8 tt;
      tt.d[0] = pk2bf(a.x, a.y); tt.d[1] = pk2bf(a.z, a.w);
      tt.d[2] = pk2bf(b.x, b.y); tt.d[3] = pk2bf(b.z, b.w);
      aS[m][kb] = tt.v;
    }
    const float* fvp = feat_v + jn*192 + rowg*24;
#pragma unroll
    for (int kv = 0; kv < 2; ++kv) {
      float f[24];
#pragma unroll
      for (int q = 0; q < 6; ++q)
        *(float4*)&f[q*4] = *(const float4*)(fvp + kv*96 + q*4);
      U8 tt;
#pragma unroll
      for (int e = 0; e < 8; e += 2) {
        tt.d[e>>1] = pk2bf(f[e*3+0]*v0 + f[e*3+1]*v1 + f[e*3+2]*v2,
                           f[e*3+3]*v0 + f[e*3+4]*v1 + f[e*3+5]*v2);
      }
      aT[m][kv] = tt.v;
    }
  }
  __syncthreads();   // BAR1: stage-1 weights + gather LDS complete

  // ---- GEMM1: msg_s = [ns | tpb] @ W0 (K=192, N=128); B shared across m ----
  float msgs[2][8][4];
  {
    f32x4 accS[2][8];
#pragma unroll
    for (int m = 0; m < 2; ++m)
#pragma unroll
      for (int cb = 0; cb < 8; ++cb) accS[m][cb] = (f32x4){0.f,0.f,0.f,0.f};
#pragma unroll
    for (int kb = 0; kb < 6; ++kb) {
      bf16x8 bw[8];
#pragma unroll
      for (int cb = 0; cb < 8; ++cb) bw[cb] = LFRAG(wbuf, 200, cb, kb);
#pragma unroll
      for (int m = 0; m < 2; ++m) {
        const bf16x8 aF = (kb < 4) ? aS[m][kb] : aT[m][kb-4];
#pragma unroll
        for (int cb = 0; cb < 8; ++cb)
          accS[m][cb] = __builtin_amdgcn_mfma_f32_16x16x32_bf16(aF, bw[cb], accS[m][cb], 0, 0, 0);
      }
    }
#pragma unroll
    for (int m = 0; m < 2; ++m)
#pragma unroll
      for (int cb = 0; cb < 8; ++cb) {
        const int col = cb*16 + colb;
        const float w0l = w0last[col];
#pragma unroll
        for (int jj = 0; jj < 4; ++jj) {
          const float v = (accS[m][cb][jj] + w0l) * RS193;
          msgs[m][cb][jj] = v;
          bA[2*w+m][rowg*4 + jj][col] = f2bf(v);
        }
      }
  }

  // ---- S_b = ns @ W1B (K=128, N=64) — accB lives through MLP phases ----
  f32x4 accB[2][4];
#pragma unroll
  for (int m = 0; m < 2; ++m)
#pragma unroll
    for (int cb = 0; cb < 4; ++cb) accB[m][cb] = (f32x4){0.f,0.f,0.f,0.f};
#pragma unroll
  for (int kb = 0; kb < 4; ++kb) {
    bf16x8 bw[4];
#pragma unroll
    for (int cb = 0; cb < 4; ++cb) bw[cb] = LFRAG(wbuf2, 136, cb, kb);
#pragma unroll
    for (int m = 0; m < 2; ++m)
#pragma unroll
      for (int cb = 0; cb < 4; ++cb)
        accB[m][cb] = __builtin_amdgcn_mfma_f32_16x16x32_bf16(aS[m][kb], bw[cb], accB[m][cb], 0, 0, 0);
  }

  __syncthreads();   // BAR2: all waves done with W0/W1B
  stage(wbuf,  Wc + OFF_PH2, PH2_SZ, t);   // WM1 + WM1E + W1A + W1C (contiguous)
  stage(wbuf2, Wc + OFF_WM2, 13824,  t);
  __syncthreads();   // BAR3: phase-2 weights ready

  // ---- aFS loads hoisted: issue early, consume in MLP1's center-feat part ----
  bf16x8 aFS[2][4];
#pragma unroll
  for (int m = 0; m < 2; ++m) {
    const float* fcp = feat_s + (p0+m)*128 + rowg*8;
#pragma unroll
    for (int kb = 0; kb < 4; ++kb) {
      const float4 a = *(const float4*)(fcp + kb*32);
      const float4 b = *(const float4*)(fcp + kb*32 + 4);
      U8 tt;
      tt.d[0] = pk2bf(a.x, a.y); tt.d[1] = pk2bf(a.z, a.w);
      tt.d[2] = pk2bf(b.x, b.y); tt.d[3] = pk2bf(b.z, b.w);
      aFS[m][kb] = tt.v;
    }
  }

  // ---- MLP1: [msg_s | rad] @ WM1 + feat_s(center) @ WM1E  (K=170+128, N=48) ----
  {
    f32x4 accH[2][3];
#pragma unroll
    for (int m = 0; m < 2; ++m)
#pragma unroll
      for (int cb = 0; cb < 3; ++cb) accH[m][cb] = (f32x4){0.f,0.f,0.f,0.f};
    // msg_s part (kb 0..3, A from bA)
#pragma unroll
    for (int kb = 0; kb < 4; ++kb) {
      bf16x8 bw[3];
#pragma unroll
      for (int cb = 0; cb < 3; ++cb) bw[cb] = LFRAG(wbuf + P2_WM1, 200, cb, kb);
#pragma unroll
      for (int m = 0; m < 2; ++m) {
        const bf16x8 aF = *(const bf16x8*)&bA[2*w+m][colb][kb*32 + rowg*8];
#pragma unroll
        for (int cb = 0; cb < 3; ++cb)
          accH[m][cb] = __builtin_amdgcn_mfma_f32_16x16x32_bf16(aF, bw[cb], accH[m][cb], 0, 0, 0);
      }
    }
    // rad part (kb 4..5): A-fragments built in registers (lane's row = colb)
    bf16x8 radF[2][2];
#pragma unroll
    for (int m = 0; m < 2; ++m) {
      const float x = s_vec[2*w+m][colb][3] * (1.0f/32.0f);
      U8 r0, r1;
#pragma unroll
      for (int e = 0; e < 8; ++e) {
        const int ch0 = rowg*8 + e;
        const int ch1 = 32 + rowg*8 + e;
        const float s0 = (x < 1.0f) ? __sinf(3.14159265f*(float)(ch0+1)*x) * RINV : 0.0f;
        const float s1 = (ch1 < 42 && x < 1.0f) ? __sinf(3.14159265f*(float)(ch1+1)*x) * RINV : 0.0f;
        r0.u[e] = f2bf(s0); r1.u[e] = f2bf(s1);
      }
      radF[m][0] = r0.v; radF[m][1] = r1.v;
    }
#pragma unroll
    for (int kb = 4; kb < 6; ++kb) {
      bf16x8 bw[3];
#pragma unroll
      for (int cb = 0; cb < 3; ++cb) bw[cb] = LFRAG(wbuf + P2_WM1, 200, cb, kb);
#pragma unroll
      for (int m = 0; m < 2; ++m)
#pragma unroll
        for (int cb = 0; cb < 3; ++cb)
          accH[m][cb] = __builtin_amdgcn_mfma_f32_16x16x32_bf16(radF[m][kb-4], bw[cb], accH[m][cb], 0, 0, 0);
    }
    // center-feat part (aFS preloaded)
#pragma unroll
    for (int kb = 0; kb < 4; ++kb) {
      bf16x8 bw[3];
#pragma unroll
      for (int cb = 0; cb < 3; ++cb) bw[cb] = LFRAG(wbuf + P2_WM1E, 136, cb, kb);
#pragma unroll
      for (int m = 0; m < 2; ++m)
#pragma unroll
        for (int cb = 0; cb < 3; ++cb)
          accH[m][cb] = __builtin_amdgcn_mfma_f32_16x16x32_bf16(aFS[m][kb], bw[cb], accH[m][cb], 0, 0, 0);
    }
    // h -> bA cols 0..63 (overwrites msg_s low cols; msg_s kept in msgs regs)
#pragma unroll
    for (int m = 0; m < 2; ++m) {
#pragma unroll
      for (int cb = 0; cb < 3; ++cb) {
        const int rr = cb*16 + colb;
        const float bv = (rr < 42) ? b1[rr] : 0.f;
#pragma unroll
        for (int jj = 0; jj < 4; ++jj) {
          float hv = 0.f;
          if (rr < 42) {
            const float z = accH[m][cb][jj] * RS298 + bv;
            hv = z / (1.0f + __expf(-z));
          }
          bA[2*w+m][rowg*4 + jj][rr] = f2bf(hv);
        }
      }
      *(u16x4*)&bA[2*w+m][colb][48 + rowg*4] = (u16x4){0,0,0,0};
    }
  }

  // ---- P-phase aV loads hoisted: issue before MLP2, consume after ----
  bf16x8 aV0[2][2], aV1[2][2], aV2[2][2];
#pragma unroll
  for (int m = 0; m < 2; ++m) {
    const int pt = 2*w + m;
    const int jn = s_nei[pt][colb];
    const float* fvp = feat_v + jn*192 + rowg*24;
#pragma unroll
    for (int kv = 0; kv < 2; ++kv) {
      float f[24];
#pragma unroll
      for (int q = 0; q < 6; ++q)
        *(float4*)&f[q*4] = *(const float4*)(fvp + kv*96 + q*4);
      U8 t0, t1, t2;
#pragma unroll
      for (int e = 0; e < 8; e += 2) {
        t0.d[e>>1] = pk2bf(f[e*3+0], f[e*3+3]);
        t1.d[e>>1] = pk2bf(f[e*3+1], f[e*3+4]);
        t2.d[e>>1] = pk2bf(f[e*3+2], f[e*3+5]);
      }
      aV0[m][kv] = t0.v; aV1[m][kv] = t1.v; aV2[m][kv] = t2.v;
    }
  }

  // ---- MLP2a: mix_s = h @ WM2[:,0:128] -> out_s (msgs from regs) ----
  {
    f32x4 accM[2][8];
#pragma unroll
    for (int m = 0; m < 2; ++m)
#pragma unroll
      for (int cb = 0; cb < 8; ++cb) accM[m][cb] = (f32x4){0.f,0.f,0.f,0.f};
#pragma unroll
    for (int kb = 0; kb < 2; ++kb) {
      bf16x8 bw[8];
#pragma unroll
      for (int cb = 0; cb < 8; ++cb) bw[cb] = LFRAG(wbuf2, 72, cb, kb);
#pragma unroll
      for (int m = 0; m < 2; ++m) {
        const bf16x8 aF = *(const bf16x8*)&bA[2*w+m][colb][kb*32 + rowg*8];
#pragma unroll
        for (int cb = 0; cb < 8; ++cb)
          accM[m][cb] = __builtin_amdgcn_mfma_f32_16x16x32_bf16(aF, bw[cb], accM[m][cb], 0, 0, 0);
      }
    }
#pragma unroll
    for (int m = 0; m < 2; ++m) {
      const int pm = p0 + m;
      float s_lo = 0.f, s_hi = 0.f;
#pragma unroll
      for (int cb = 0; cb < 8; ++cb) {
        const int col = cb*16 + colb;
        const float b2v = b2[col];
        float s = 0.f;
#pragma unroll
        for (int jj = 0; jj < 4; ++jj)
          s += msgs[m][cb][jj] * (accM[m][cb][jj] * RS42 + b2v);
        s += __shfl_xor(s, 16);
        s += __shfl_xor(s, 32);
        if (cb == rowg)     s_lo = s;
        if (cb == rowg + 4) s_hi = s;
      }
      out[pm*128 + l]      = feat_s[pm*128 + l]      + s_lo * 0.0625f;
      out[pm*128 + 64 + l] = feat_s[pm*128 + 64 + l] + s_hi * 0.0625f;
    }
  }

  // ---- MLP2b: mix_v = h @ WM2[:,128:192] ----
  f32x4 accMv[2][4];
#pragma unroll
  for (int m = 0; m < 2; ++m)
#pragma unroll
    for (int cb = 0; cb < 4; ++cb) accMv[m][cb] = (f32x4){0.f,0.f,0.f,0.f};
#pragma unroll
  for (int kb = 0; kb < 2; ++kb) {
    bf16x8 bw[4];
#pragma unroll
    for (int cb = 0; cb < 4; ++cb) bw[cb] = LFRAG(wbuf2, 72, cb + 8, kb);
#pragma unroll
    for (int m = 0; m < 2; ++m) {
      const bf16x8 aF = *(const bf16x8*)&bA[2*w+m][colb][kb*32 + rowg*8];
#pragma unroll
      for (int cb = 0; cb < 4; ++cb)
        accMv[m][cb] = __builtin_amdgcn_mfma_f32_16x16x32_bf16(aF, bw[cb], accMv[m][cb], 0, 0, 0);
    }
  }

  // ---- P-phase: msg_v per-cb from wbuf tail (aV already in regs) ----
  float sh[2][4][3];
#pragma unroll
  for (int m = 0; m < 2; ++m)
#pragma unroll
    for (int jj = 0; jj < 4; ++jj) {
      const int rr = rowg*4 + jj;
      sh[m][jj][0] = SQ3 * s_vec[2*w+m][rr][0];
      sh[m][jj][1] = SQ3 * s_vec[2*w+m][rr][1];
      sh[m][jj][2] = SQ3 * s_vec[2*w+m][rr][2];
    }
  float ov0[2] = {0.f,0.f}, ov1[2] = {0.f,0.f}, ov2[2] = {0.f,0.f};
#pragma unroll
  for (int cb = 0; cb < 4; ++cb) {
    f32x4 aA0[2], aA1[2], aA2[2], aC0[2], aC1[2], aC2[2];
#pragma unroll
    for (int m = 0; m < 2; ++m) {
      aA0[m] = (f32x4){0.f,0.f,0.f,0.f}; aA1[m] = (f32x4){0.f,0.f,0.f,0.f}; aA2[m] = (f32x4){0.f,0.f,0.f,0.f};
      aC0[m] = (f32x4){0.f,0.f,0.f,0.f}; aC1[m] = (f32x4){0.f,0.f,0.f,0.f}; aC2[m] = (f32x4){0.f,0.f,0.f,0.f};
    }
#pragma unroll
    for (int kv = 0; kv < 2; ++kv) {
      const bf16x8 ba = LFRAG(wbuf + P2_W1A, 72, cb, kv);
      const bf16x8 bc = LFRAG(wbuf + P2_W1C, 72, cb, kv);
#pragma unroll
      for (int m = 0; m < 2; ++m) {
        aA0[m] = __builtin_amdgcn_mfma_f32_16x16x32_bf16(aV0[m][kv], ba, aA0[m], 0, 0, 0);
        aA1[m] = __builtin_amdgcn_mfma_f32_16x16x32_bf16(aV1[m][kv], ba, aA1[m], 0, 0, 0);
        aA2[m] = __builtin_amdgcn_mfma_f32_16x16x32_bf16(aV2[m][kv], ba, aA2[m], 0, 0, 0);
        aC0[m] = __builtin_amdgcn_mfma_f32_16x16x32_bf16(aV0[m][kv], bc, aC0[m], 0, 0, 0);
        aC1[m] = __builtin_amdgcn_mfma_f32_16x16x32_bf16(aV1[m][kv], bc, aC1[m], 0, 0, 0);
        aC2[m] = __builtin_amdgcn_mfma_f32_16x16x32_bf16(aV2[m][kv], bc, aC2[m], 0, 0, 0);
      }
    }
    const int d = cb*16 + colb;
    const float wl = w1last[d];
    const float b2v = b2[128 + d];
#pragma unroll
    for (int m = 0; m < 2; ++m) {
      float sv0 = 0.f, sv1 = 0.f, sv2 = 0.f;
#pragma unroll
      for (int jj = 0; jj < 4; ++jj) {
        const float bb = accB[m][cb][jj] + wl;
        const float h0 = sh[m][jj][0], h1 = sh[m][jj][1], h2 = sh[m][jj][2];
        const float m0 = (aA0[m][jj] + h0*bb + (h1*aC2[m][jj] - h2*aC1[m][jj])*IS2) * RS257;
        const float m1 = (aA1[m][jj] + h1*bb + (h2*aC0[m][jj] - h0*aC2[m][jj])*IS2) * RS257;
        const float m2 = (aA2[m][jj] + h2*bb + (h0*aC1[m][jj] - h1*aC0[m][jj])*IS2) * RS257;
        const float mx = accMv[m][cb][jj] * RS42 + b2v;
        sv0 += m0 * mx; sv1 += m1 * mx; sv2 += m2 * mx;
      }
      sv0 += __shfl_xor(sv0, 16); sv0 += __shfl_xor(sv0, 32);
      sv1 += __shfl_xor(sv1, 16); sv1 += __shfl_xor(sv1, 32);
      sv2 += __shfl_xor(sv2, 16); sv2 += __shfl_xor(sv2, 32);
      if (cb == rowg) { ov0[m] = sv0 * 0.0625f; ov1[m] = sv1 * 0.0625f; ov2[m] = sv2 * 0.0625f; }
    }
  }

  // out_v (lane l owns d = l) + coord move, per m
#pragma unroll
  for (int m = 0; m < 2; ++m) {
    const int pm = p0 + m;
    const int vb = pm*192 + l*3;
    out[NPTS*128 + vb + 0] = feat_v[vb + 0] + ov0[m];
    out[NPTS*128 + vb + 1] = feat_v[vb + 1] + ov1[m];
    out[NPTS*128 + vb + 2] = feat_v[vb + 2] + ov2[m];
    const float wm = w_move[l];
    float cn0 = ov0[m] * wm, cn1 = ov1[m] * wm, cn2 = ov2[m] * wm;
#pragma unroll
    for (int off = 1; off <= 32; off <<= 1) {
      cn0 += __shfl_xor(cn0, off);
      cn1 += __shfl_xor(cn1, off);
      cn2 += __shfl_xor(cn2, off);
    }
    if (l == 0) {
      const int oc = NPTS*(128+192) + pm*3;
      out[oc+0] = coord[pm*3+0] + 1.25e-4f * cn0;
      out[oc+1] = coord[pm*3+1] + 1.25e-4f * cn1;
      out[oc+2] = coord[pm*3+2] + 1.25e-4f * cn2;
    }
  }
}

} // namespace

extern "C" void kernel_launch(void* const* d_in, const int* in_sizes, int n_in,
                              void* d_out, int out_size, void* d_ws, size_t ws_size,
                              hipStream_t stream) {
  const float* coord  = (const float*)d_in[0];
  const float* feat_s = (const float*)d_in[1];
  const float* feat_v = (const float*)d_in[2];
  // d_in[3] = mask: all-true, unused
  const float* W0     = (const float*)d_in[4];
  const float* W1     = (const float*)d_in[5];
  const float* w1     = (const float*)d_in[6];
  const float* b1     = (const float*)d_in[7];
  const float* w2     = (const float*)d_in[8];
  const float* b2     = (const float*)d_in[9];
  const float* wmove  = (const float*)d_in[10];
  float* out = (float*)d_out;

  char* ws = (char*)d_ws;
  int*   nei     = (int*)  (ws + 0);          // 524288 B (only 16 edge rows used)
  u16*   Wrep    = (u16*)  (ws + 524288);     // 8 x 146944 = 1175552 B
  float* w0last  = (float*)(ws + 1699840);    // 512 B
  float* w1last  = (float*)(ws + 1700352);    // 256 B
  u64*   packed4 = (u64*)  (ws + 1700608);    // 8192*4*8 = 262144 B

  setup_all<<<2352, 256, 0, stream>>>(coord, W0, W1, w1, w2, Wrep, w0last, w1last,
                                      nei, packed4);
  conv_mfma<<<NPTS/16, 512, 0, stream>>>(coord, feat_s, feat_v, nei, packed4, Wrep,
                                         w0last, w1last, b1, b2, wmove, out);
}

// Round 15
// 101.710 us; speedup vs baseline: 1.0562x; 1.0562x over previous
//
#include <hip/hip_runtime.h>
#include <math.h>

namespace {

typedef unsigned short u16;
typedef short bf16x8 __attribute__((ext_vector_type(8)));
typedef float f32x4 __attribute__((ext_vector_type(4)));
typedef unsigned short u16x4 __attribute__((ext_vector_type(4)));
typedef unsigned short u16x2 __attribute__((ext_vector_type(2)));
typedef unsigned long long u64;

constexpr int NPTS = 8192;
constexpr int KNB  = 16;

// padded bf16 weight-copy layout (u16 offsets; all row strides 16B multiples)
constexpr int OFF_W0   = 0;       // [128][200] = 25600
constexpr int OFF_PH2  = 25600;   // phase-2 contiguous block:
constexpr int P2_WM1   = 0;       //   [48][200] = 9600   (mix_in dims 0..169)
constexpr int P2_WM1E  = 9600;    //   [48][136] = 6528   (feat_s dims 170..297)
constexpr int P2_W1A   = 16128;   //   [64][72]  = 4608
constexpr int P2_W1C   = 20736;   //   [64][72]  = 4608
constexpr int PH2_SZ   = 25344;
constexpr int OFF_W1B  = 50944;   // [64][136] = 8704
constexpr int OFF_WM2  = 59648;   // [192][72] = 13824
constexpr int WCOPY    = 73472;   // u16 per copy (146944 B)
constexpr int NCOPY    = 8;

__device__ __forceinline__ u16 f2bf(float f) {           // round-half-up, 2 ops
  return (u16)((__float_as_uint(f) + 0x8000u) >> 16);
}
// pack 2 floats -> 2 bf16 in one dword: (hi=b, lo=a); 3 VALU ops
__device__ __forceinline__ unsigned int pk2bf(float a, float b) {
  const unsigned int ua = __float_as_uint(a) + 0x8000u;
  const unsigned int ub = __float_as_uint(b) + 0x8000u;
  return __builtin_amdgcn_perm(ub, ua, 0x07060302);
}

__device__ __forceinline__ void wave_argmin(float& best, int& bj) {
#pragma unroll
  for (int off = 32; off; off >>= 1) {
    float ob = __shfl_xor(best, off);
    int   oj = __shfl_xor(bj, off);
    if (ob < best || (ob == best && oj < bj)) { best = ob; bj = oj; }
  }
}

// ---------------- setup: prep (0..287) + interior KNN quarters (288..2335) + edge (2336..2351) ----------------
// Interior KNN writes packed4[pp*4+q] with a PLAIN store (each (point,quarter)
// pair owned by exactly one wave) -> no init, no atomics. u64 order preserves
// exact (d2, lower-j) lexicographic tie-break.
__global__ __launch_bounds__(256) void setup_all(
    const float* __restrict__ coord,
    const float* __restrict__ W0, const float* __restrict__ W1,
    const float* __restrict__ w1, const float* __restrict__ w2,
    u16* __restrict__ Wrep, float* __restrict__ w0last, float* __restrict__ w1last,
    int* __restrict__ nei, u64* __restrict__ packed4) {
  const int b = blockIdx.x;
  if (b < 288) {
    const int t = b * 256 + threadIdx.x;
    if (t < WCOPY) {
      u16 val = 0;
      int i = t;
      if (i < 25600)                 { const int d = i/200, c = i%200; if (c < 192) val = f2bf(W0[c*128 + d]); }
      else if ((i -= 25600) < 9600)  { const int r = i/200, c = i%200; if (r < 42 && c < 170) val = f2bf(w1[c*42 + r]); }
      else if ((i -= 9600)  < 6528)  { const int r = i/136, c = i%136; if (r < 42 && c < 128) val = f2bf(w1[(170+c)*42 + r]); }
      else if ((i -= 6528)  < 4608)  { const int d = i/72,  c = i%72;  if (c < 64)  val = f2bf(W1[c*64 + d]); }
      else if ((i -= 4608)  < 4608)  { const int d = i/72,  c = i%72;  if (c < 64)  val = f2bf(W1[(192+c)*64 + d]); }
      else if ((i -= 4608)  < 8704)  { const int d = i/136, c = i%136; if (c < 128) val = f2bf(W1[(64+c)*64 + d]); }
      else { i -= 8704;                const int e = i/72,  rr = i%72; if (rr < 42) val = f2bf(w2[rr*192 + e]); }
#pragma unroll
      for (int cp = 0; cp < NCOPY; ++cp) Wrep[cp*WCOPY + t] = val;
      return;
    }
    int t2 = t - WCOPY;
    if (t2 < 128) { w0last[t2] = W0[192*128 + t2]; return; }
    t2 -= 128;
    if (t2 < 64)  { w1last[t2] = W1[256*64 + t2]; return; }
    return;
  }
  if (b < 2336) {
    const int qb = b - 288;
    const int g  = qb >> 2;          // 0..511
    const int q  = qb & 3;           // range quarter
    const int lane = threadIdx.x & 63;
    const int wid  = g * 4 + (threadIdx.x >> 6);
    int p[4]; float cx[4], cy[4], cz[4], best[4]; int bj[4];
#pragma unroll
    for (int t = 0; t < 4; ++t) {
      p[t] = wid + 2048 * t;
      cx[t] = coord[3*p[t]+0]; cy[t] = coord[3*p[t]+1]; cz[t] = coord[3*p[t]+2];
      best[t] = 3.0e38f; bj[t] = NPTS;
    }
    const int j0 = q * 2048;
    for (int j = j0 + lane; j < j0 + 2048; j += 64) {
      const float x = coord[3*j+0], y = coord[3*j+1], z = coord[3*j+2];
#pragma unroll
      for (int t = 0; t < 4; ++t) {
        int dd = j - p[t]; dd = dd < 0 ? -dd : dd;
        const float dx = x-cx[t], dy = y-cy[t], dz = z-cz[t];
        const float d2 = dx*dx + dy*dy + dz*dz;
        if (dd > 8 && d2 < best[t]) { best[t] = d2; bj[t] = j; }
      }
    }
#pragma unroll
    for (int t = 0; t < 4; ++t) {
      wave_argmin(best[t], bj[t]);
      const int pp = p[t];
      if (lane == 0 && pp >= 8 && pp < NPTS-8)
        packed4[pp*4 + q] = ((u64)__float_as_uint(best[t]) << 32) | (unsigned)bj[t];
    }
    return;
  }
  // edge KNN: 1 block per edge point (16 blocks) -> nei table rows
  {
    const int eb = b - 2336;
    const int n = (eb < 8) ? eb : (NPTS - 16 + eb);
    const int tid = threadIdx.x;
    const int lane = tid & 63;
    const int wv = tid >> 6;
    __shared__ float l_best[4];
    __shared__ int   l_bj[4];
    __shared__ int   l_sel;
    __shared__ int   s_sel[9];
    const float cx = coord[3*n+0], cy = coord[3*n+1], cz = coord[3*n+2];
    float d2v[32];
    unsigned int alive = 0;
#pragma unroll
    for (int q = 0; q < 32; ++q) {
      const int j = tid + q * 256;
      int dd = j - n; dd = dd < 0 ? -dd : dd;
      const float dx = coord[3*j+0]-cx, dy = coord[3*j+1]-cy, dz = coord[3*j+2]-cz;
      d2v[q] = dx*dx + dy*dy + dz*dz;
      if (dd > 8) alive |= (1u << q);
    }
    const int lo = (n-8 < 0) ? 0 : n-8;
    const int hi = (n+8 > NPTS-1) ? NPTS-1 : n+8;
    const int s  = (KNB + 1) - (hi - lo);
    for (int p = 0; p < s; ++p) {
      float best = 3.0e38f; int bj = NPTS;
#pragma unroll
      for (int q = 0; q < 32; ++q) {
        if ((alive >> q) & 1u) {
          const int j = tid + q * 256;
          if (d2v[q] < best) { best = d2v[q]; bj = j; }
        }
      }
      wave_argmin(best, bj);
      if (lane == 0) { l_best[wv] = best; l_bj[wv] = bj; }
      __syncthreads();
      if (tid == 0) {
        float bb = l_best[0]; int jj = l_bj[0];
        for (int w2 = 1; w2 < 4; ++w2)
          if (l_best[w2] < bb || (l_best[w2] == bb && l_bj[w2] < jj)) { bb = l_best[w2]; jj = l_bj[w2]; }
        l_sel = jj; s_sel[p] = jj;
      }
      __syncthreads();
      const int dq = l_sel - tid;
      if (dq >= 0 && (dq & 255) == 0) alive &= ~(1u << (dq >> 8));
      __syncthreads();
    }
    if (tid == 0) {
      const int first = (lo == n) ? (lo + 1) : lo;
      int idx = 0;
      for (int j = lo; j <= hi; ++j) {
        if (j == n || j == first) continue;
        nei[n*KNB + (idx++)] = j;
      }
      for (int p = 0; p < s; ++p) nei[n*KNB + (idx++)] = s_sel[p];
    }
  }
}

// async block-cooperative staging: global -> LDS direct. 512 threads x 16B.
__device__ __forceinline__ void stage(u16* dst, const u16* src, int n, int t) {
  for (int i = t*8; i < n; i += 4096)
    __builtin_amdgcn_global_load_lds(
        (const __attribute__((address_space(1))) unsigned int*)(src + i),
        (__attribute__((address_space(3))) unsigned int*)(dst + i), 16, 0, 0);
}

// ---------------- fused MFMA conv: 16 pts/block = 8 waves x 2 pts, shared B-frags ----------------
#define LFRAG(BUF, ldk, cb, kb) (*(const bf16x8*)&(BUF)[((cb)*16 + colb)*(ldk) + (kb)*32 + rowg*8])

__global__ __launch_bounds__(512, 2) void conv_mfma(
    const float* __restrict__ coord,
    const float* __restrict__ feat_s,
    const float* __restrict__ feat_v,
    const int*   __restrict__ nei,
    const u64*   __restrict__ packed4,
    const u16*   __restrict__ Wrep,
    const float* __restrict__ w0last,
    const float* __restrict__ w1last,
    const float* __restrict__ b1,
    const float* __restrict__ b2,
    const float* __restrict__ w_move,
    float* __restrict__ out) {

  __shared__ __align__(16) u16 wbuf[25600];   // W0 -> {WM1, WM1E, W1A, W1C}
  __shared__ __align__(16) u16 wbuf2[13824];  // W1B -> WM2
  __shared__ __align__(16) u16 bA[16][16][136];
  __shared__ float s_vec[16][16][4];
  __shared__ int   s_nei[16][16];

  const int t = threadIdx.x;
  const int w = t >> 6;
  const int l = t & 63;
  const int colb = l & 15;
  const int rowg = l >> 4;
  const int nb = blockIdx.x * 16;
  const int p0 = nb + 2*w;     // wave's two points: p0, p0+1
  const u16* Wc = Wrep + (blockIdx.x & 7) * WCOPY;

  constexpr float RS193 = 0.07198158f;
  constexpr float RS257 = 0.06237829f;
  constexpr float RS298 = 0.05792841f;
  constexpr float RS42  = 0.15430335f;
  constexpr float IS2   = 0.70710678f;
  constexpr float SQ3   = 1.73205081f;
  constexpr float RINV  = 0.21693046f;

  // ---- async stage of phase-1 weights ----
  stage(wbuf,  Wc + OFF_W0,  25600, t);
  stage(wbuf2, Wc + OFF_W1B, 8704,  t);

  union U8 { unsigned int d[4]; u16 u[8]; bf16x8 v; };
  bf16x8 aS[2][4], aT[2][2];

  // ---- gather (wave-local; overlaps staging latency) ----
#pragma unroll
  for (int m = 0; m < 2; ++m) {
    const int pt = 2*w + m;
    const int pm = p0 + m;
    if (l < 16) {
      int j;
      const bool is_edge = (pm < 8) || (pm >= NPTS-8);
      if (is_edge) {
        j = nei[pm*KNB + l];
      } else if (l < 15) {
        j = pm - 7 + l + (l >= 7 ? 1 : 0);          // band neighbor (analytic)
      } else {
        const u64* pp4 = packed4 + pm*4;            // min of 4 quarter-candidates
        u64 q0 = pp4[0], q1 = pp4[1], q2 = pp4[2], q3 = pp4[3];
        u64 mn = q0 < q1 ? q0 : q1;
        u64 mn2 = q2 < q3 ? q2 : q3;
        mn = mn < mn2 ? mn : mn2;
        j = (int)(unsigned)(mn & 0xFFFFFFFFull);
      }
      s_nei[pt][l] = j;
      const float v0 = coord[3*j+0] - coord[3*pm+0];
      const float v1 = coord[3*j+1] - coord[3*pm+1];
      const float v2 = coord[3*j+2] - coord[3*pm+2];
      const float n2 = v0*v0 + v1*v1 + v2*v2;
      s_vec[pt][l][0] = v0; s_vec[pt][l][1] = v1; s_vec[pt][l][2] = v2;
      s_vec[pt][l][3] = sqrtf(n2 == 0.0f ? 1.0f : n2);
    }
    const int jn = s_nei[pt][colb];
    const float v0 = s_vec[pt][colb][0], v1 = s_vec[pt][colb][1], v2 = s_vec[pt][colb][2];
    const float* fsp = feat_s + jn*128 + rowg*8;
#pragma unroll
    for (int kb = 0; kb < 4; ++kb) {
      const float4 a = *(const float4*)(fsp + kb*32);
      const float4 b = *(const float4*)(fsp + kb*32 + 4);
      U8 tt;
      tt.d[0] = pk2bf(a.x, a.y); tt.d[1] = pk2bf(a.z, a.w);
      tt.d[2] = pk2bf(b.x, b.y); tt.d[3] = pk2bf(b.z, b.w);
      aS[m][kb] = tt.v;
    }
    const float* fvp = feat_v + jn*192 + rowg*24;
#pragma unroll
    for (int kv = 0; kv < 2; ++kv) {
      float f[24];
#pragma unroll
      for (int q = 0; q < 6; ++q)
        *(float4*)&f[q*4] = *(const float4*)(fvp + kv*96 + q*4);
      U8 tt;
#pragma unroll
      for (int e = 0; e < 8; e += 2) {
        tt.d[e>>1] = pk2bf(f[e*3+0]*v0 + f[e*3+1]*v1 + f[e*3+2]*v2,
                           f[e*3+3]*v0 + f[e*3+4]*v1 + f[e*3+5]*v2);
      }
      aT[m][kv] = tt.v;
    }
  }
  __syncthreads();   // BAR1: stage-1 weights + gather LDS complete

  // ---- GEMM1: msg_s = [ns | tpb] @ W0 (K=192, N=128); B shared across m ----
  float msgs[2][8][4];
  {
    f32x4 accS[2][8];
#pragma unroll
    for (int m = 0; m < 2; ++m)
#pragma unroll
      for (int cb = 0; cb < 8; ++cb) accS[m][cb] = (f32x4){0.f,0.f,0.f,0.f};
#pragma unroll
    for (int kb = 0; kb < 6; ++kb) {
      bf16x8 bw[8];
#pragma unroll
      for (int cb = 0; cb < 8; ++cb) bw[cb] = LFRAG(wbuf, 200, cb, kb);
#pragma unroll
      for (int m = 0; m < 2; ++m) {
        const bf16x8 aF = (kb < 4) ? aS[m][kb] : aT[m][kb-4];
#pragma unroll
        for (int cb = 0; cb < 8; ++cb)
          accS[m][cb] = __builtin_amdgcn_mfma_f32_16x16x32_bf16(aF, bw[cb], accS[m][cb], 0, 0, 0);
      }
    }
#pragma unroll
    for (int m = 0; m < 2; ++m)
#pragma unroll
      for (int cb = 0; cb < 8; ++cb) {
        const int col = cb*16 + colb;
        const float w0l = w0last[col];
#pragma unroll
        for (int jj = 0; jj < 4; ++jj) {
          const float v = (accS[m][cb][jj] + w0l) * RS193;
          msgs[m][cb][jj] = v;
          bA[2*w+m][rowg*4 + jj][col] = f2bf(v);
        }
      }
  }

  // ---- S_b = ns @ W1B (K=128, N=64) — accB lives through MLP phases ----
  f32x4 accB[2][4];
#pragma unroll
  for (int m = 0; m < 2; ++m)
#pragma unroll
    for (int cb = 0; cb < 4; ++cb) accB[m][cb] = (f32x4){0.f,0.f,0.f,0.f};
#pragma unroll
  for (int kb = 0; kb < 4; ++kb) {
    bf16x8 bw[4];
#pragma unroll
    for (int cb = 0; cb < 4; ++cb) bw[cb] = LFRAG(wbuf2, 136, cb, kb);
#pragma unroll
    for (int m = 0; m < 2; ++m)
#pragma unroll
      for (int cb = 0; cb < 4; ++cb)
        accB[m][cb] = __builtin_amdgcn_mfma_f32_16x16x32_bf16(aS[m][kb], bw[cb], accB[m][cb], 0, 0, 0);
  }

  __syncthreads();   // BAR2: all waves done with W0/W1B
  stage(wbuf,  Wc + OFF_PH2, PH2_SZ, t);   // WM1 + WM1E + W1A + W1C (contiguous)
  stage(wbuf2, Wc + OFF_WM2, 13824,  t);
  __syncthreads();   // BAR3: phase-2 weights ready

  // ---- MLP1: [msg_s | rad] @ WM1 + feat_s(center) @ WM1E  (K=170+128, N=48) ----
  {
    f32x4 accH[2][3];
#pragma unroll
    for (int m = 0; m < 2; ++m)
#pragma unroll
      for (int cb = 0; cb < 3; ++cb) accH[m][cb] = (f32x4){0.f,0.f,0.f,0.f};
    // msg_s part (kb 0..3, A from bA)
#pragma unroll
    for (int kb = 0; kb < 4; ++kb) {
      bf16x8 bw[3];
#pragma unroll
      for (int cb = 0; cb < 3; ++cb) bw[cb] = LFRAG(wbuf + P2_WM1, 200, cb, kb);
#pragma unroll
      for (int m = 0; m < 2; ++m) {
        const bf16x8 aF = *(const bf16x8*)&bA[2*w+m][colb][kb*32 + rowg*8];
#pragma unroll
        for (int cb = 0; cb < 3; ++cb)
          accH[m][cb] = __builtin_amdgcn_mfma_f32_16x16x32_bf16(aF, bw[cb], accH[m][cb], 0, 0, 0);
      }
    }
    // rad part (kb 4..5): A-fragments built in registers (lane's row = colb)
    bf16x8 radF[2][2];
#pragma unroll
    for (int m = 0; m < 2; ++m) {
      const float x = s_vec[2*w+m][colb][3] * (1.0f/32.0f);
      U8 r0, r1;
#pragma unroll
      for (int e = 0; e < 8; ++e) {
        const int ch0 = rowg*8 + e;
        const int ch1 = 32 + rowg*8 + e;
        const float s0 = (x < 1.0f) ? __sinf(3.14159265f*(float)(ch0+1)*x) * RINV : 0.0f;
        const float s1 = (ch1 < 42 && x < 1.0f) ? __sinf(3.14159265f*(float)(ch1+1)*x) * RINV : 0.0f;
        r0.u[e] = f2bf(s0); r1.u[e] = f2bf(s1);
      }
      radF[m][0] = r0.v; radF[m][1] = r1.v;
    }
#pragma unroll
    for (int kb = 4; kb < 6; ++kb) {
      bf16x8 bw[3];
#pragma unroll
      for (int cb = 0; cb < 3; ++cb) bw[cb] = LFRAG(wbuf + P2_WM1, 200, cb, kb);
#pragma unroll
      for (int m = 0; m < 2; ++m)
#pragma unroll
        for (int cb = 0; cb < 3; ++cb)
          accH[m][cb] = __builtin_amdgcn_mfma_f32_16x16x32_bf16(radF[m][kb-4], bw[cb], accH[m][cb], 0, 0, 0);
    }
    // center-feat part: aFS loaded here (broadcast rows)
#pragma unroll
    for (int kb = 0; kb < 4; ++kb) {
      bf16x8 bw[3];
#pragma unroll
      for (int cb = 0; cb < 3; ++cb) bw[cb] = LFRAG(wbuf + P2_WM1E, 136, cb, kb);
#pragma unroll
      for (int m = 0; m < 2; ++m) {
        const float* fcp = feat_s + (p0+m)*128 + rowg*8;
        const float4 a = *(const float4*)(fcp + kb*32);
        const float4 b = *(const float4*)(fcp + kb*32 + 4);
        U8 tt;
        tt.d[0] = pk2bf(a.x, a.y); tt.d[1] = pk2bf(a.z, a.w);
        tt.d[2] = pk2bf(b.x, b.y); tt.d[3] = pk2bf(b.z, b.w);
#pragma unroll
        for (int cb = 0; cb < 3; ++cb)
          accH[m][cb] = __builtin_amdgcn_mfma_f32_16x16x32_bf16(tt.v, bw[cb], accH[m][cb], 0, 0, 0);
      }
    }
    // h -> bA cols 0..63 (overwrites msg_s low cols; msg_s kept in msgs regs)
#pragma unroll
    for (int m = 0; m < 2; ++m) {
#pragma unroll
      for (int cb = 0; cb < 3; ++cb) {
        const int rr = cb*16 + colb;
        const float bv = (rr < 42) ? b1[rr] : 0.f;
#pragma unroll
        for (int jj = 0; jj < 4; ++jj) {
          float hv = 0.f;
          if (rr < 42) {
            const float z = accH[m][cb][jj] * RS298 + bv;
            hv = z / (1.0f + __expf(-z));
          }
          bA[2*w+m][rowg*4 + jj][rr] = f2bf(hv);
        }
      }
      *(u16x4*)&bA[2*w+m][colb][48 + rowg*4] = (u16x4){0,0,0,0};
    }
  }

  // ---- MLP2a: mix_s = h @ WM2[:,0:128] -> out_s (msgs from regs) ----
  {
    f32x4 accM[2][8];
#pragma unroll
    for (int m = 0; m < 2; ++m)
#pragma unroll
      for (int cb = 0; cb < 8; ++cb) accM[m][cb] = (f32x4){0.f,0.f,0.f,0.f};
#pragma unroll
    for (int kb = 0; kb < 2; ++kb) {
      bf16x8 bw[8];
#pragma unroll
      for (int cb = 0; cb < 8; ++cb) bw[cb] = LFRAG(wbuf2, 72, cb, kb);
#pragma unroll
      for (int m = 0; m < 2; ++m) {
        const bf16x8 aF = *(const bf16x8*)&bA[2*w+m][colb][kb*32 + rowg*8];
#pragma unroll
        for (int cb = 0; cb < 8; ++cb)
          accM[m][cb] = __builtin_amdgcn_mfma_f32_16x16x32_bf16(aF, bw[cb], accM[m][cb], 0, 0, 0);
      }
    }
#pragma unroll
    for (int m = 0; m < 2; ++m) {
      const int pm = p0 + m;
      float s_lo = 0.f, s_hi = 0.f;
#pragma unroll
      for (int cb = 0; cb < 8; ++cb) {
        const int col = cb*16 + colb;
        const float b2v = b2[col];
        float s = 0.f;
#pragma unroll
        for (int jj = 0; jj < 4; ++jj)
          s += msgs[m][cb][jj] * (accM[m][cb][jj] * RS42 + b2v);
        s += __shfl_xor(s, 16);
        s += __shfl_xor(s, 32);
        if (cb == rowg)     s_lo = s;
        if (cb == rowg + 4) s_hi = s;
      }
      out[pm*128 + l]      = feat_s[pm*128 + l]      + s_lo * 0.0625f;
      out[pm*128 + 64 + l] = feat_s[pm*128 + 64 + l] + s_hi * 0.0625f;
    }
  }

  // ---- MLP2b: mix_v = h @ WM2[:,128:192] ----
  f32x4 accMv[2][4];
#pragma unroll
  for (int m = 0; m < 2; ++m)
#pragma unroll
    for (int cb = 0; cb < 4; ++cb) accMv[m][cb] = (f32x4){0.f,0.f,0.f,0.f};
#pragma unroll
  for (int kb = 0; kb < 2; ++kb) {
    bf16x8 bw[4];
#pragma unroll
    for (int cb = 0; cb < 4; ++cb) bw[cb] = LFRAG(wbuf2, 72, cb + 8, kb);
#pragma unroll
    for (int m = 0; m < 2; ++m) {
      const bf16x8 aF = *(const bf16x8*)&bA[2*w+m][colb][kb*32 + rowg*8];
#pragma unroll
      for (int cb = 0; cb < 4; ++cb)
        accMv[m][cb] = __builtin_amdgcn_mfma_f32_16x16x32_bf16(aF, bw[cb], accMv[m][cb], 0, 0, 0);
    }
  }

  // ---- P-phase: rebuild aV, msg_v per-cb from wbuf tail ----
  bf16x8 aV0[2][2], aV1[2][2], aV2[2][2];
#pragma unroll
  for (int m = 0; m < 2; ++m) {
    const int pt = 2*w + m;
    const int jn = s_nei[pt][colb];
    const float* fvp = feat_v + jn*192 + rowg*24;
#pragma unroll
    for (int kv = 0; kv < 2; ++kv) {
      float f[24];
#pragma unroll
      for (int q = 0; q < 6; ++q)
        *(float4*)&f[q*4] = *(const float4*)(fvp + kv*96 + q*4);
      U8 t0, t1, t2;
#pragma unroll
      for (int e = 0; e < 8; e += 2) {
        t0.d[e>>1] = pk2bf(f[e*3+0], f[e*3+3]);
        t1.d[e>>1] = pk2bf(f[e*3+1], f[e*3+4]);
        t2.d[e>>1] = pk2bf(f[e*3+2], f[e*3+5]);
      }
      aV0[m][kv] = t0.v; aV1[m][kv] = t1.v; aV2[m][kv] = t2.v;
    }
  }
  float sh[2][4][3];
#pragma unroll
  for (int m = 0; m < 2; ++m)
#pragma unroll
    for (int jj = 0; jj < 4; ++jj) {
      const int rr = rowg*4 + jj;
      sh[m][jj][0] = SQ3 * s_vec[2*w+m][rr][0];
      sh[m][jj][1] = SQ3 * s_vec[2*w+m][rr][1];
      sh[m][jj][2] = SQ3 * s_vec[2*w+m][rr][2];
    }
  float ov0[2] = {0.f,0.f}, ov1[2] = {0.f,0.f}, ov2[2] = {0.f,0.f};
#pragma unroll
  for (int cb = 0; cb < 4; ++cb) {
    f32x4 aA0[2], aA1[2], aA2[2], aC0[2], aC1[2], aC2[2];
#pragma unroll
    for (int m = 0; m < 2; ++m) {
      aA0[m] = (f32x4){0.f,0.f,0.f,0.f}; aA1[m] = (f32x4){0.f,0.f,0.f,0.f}; aA2[m] = (f32x4){0.f,0.f,0.f,0.f};
      aC0[m] = (f32x4){0.f,0.f,0.f,0.f}; aC1[m] = (f32x4){0.f,0.f,0.f,0.f}; aC2[m] = (f32x4){0.f,0.f,0.f,0.f};
    }
#pragma unroll
    for (int kv = 0; kv < 2; ++kv) {
      const bf16x8 ba = LFRAG(wbuf + P2_W1A, 72, cb, kv);
      const bf16x8 bc = LFRAG(wbuf + P2_W1C, 72, cb, kv);
#pragma unroll
      for (int m = 0; m < 2; ++m) {
        aA0[m] = __builtin_amdgcn_mfma_f32_16x16x32_bf16(aV0[m][kv], ba, aA0[m], 0, 0, 0);
        aA1[m] = __builtin_amdgcn_mfma_f32_16x16x32_bf16(aV1[m][kv], ba, aA1[m], 0, 0, 0);
        aA2[m] = __builtin_amdgcn_mfma_f32_16x16x32_bf16(aV2[m][kv], ba, aA2[m], 0, 0, 0);
        aC0[m] = __builtin_amdgcn_mfma_f32_16x16x32_bf16(aV0[m][kv], bc, aC0[m], 0, 0, 0);
        aC1[m] = __builtin_amdgcn_mfma_f32_16x16x32_bf16(aV1[m][kv], bc, aC1[m], 0, 0, 0);
        aC2[m] = __builtin_amdgcn_mfma_f32_16x16x32_bf16(aV2[m][kv], bc, aC2[m], 0, 0, 0);
      }
    }
    const int d = cb*16 + colb;
    const float wl = w1last[d];
    const float b2v = b2[128 + d];
#pragma unroll
    for (int m = 0; m < 2; ++m) {
      float sv0 = 0.f, sv1 = 0.f, sv2 = 0.f;
#pragma unroll
      for (int jj = 0; jj < 4; ++jj) {
        const float bb = accB[m][cb][jj] + wl;
        const float h0 = sh[m][jj][0], h1 = sh[m][jj][1], h2 = sh[m][jj][2];
        const float m0 = (aA0[m][jj] + h0*bb + (h1*aC2[m][jj] - h2*aC1[m][jj])*IS2) * RS257;
        const float m1 = (aA1[m][jj] + h1*bb + (h2*aC0[m][jj] - h0*aC2[m][jj])*IS2) * RS257;
        const float m2 = (aA2[m][jj] + h2*bb + (h0*aC1[m][jj] - h1*aC0[m][jj])*IS2) * RS257;
        const float mx = accMv[m][cb][jj] * RS42 + b2v;
        sv0 += m0 * mx; sv1 += m1 * mx; sv2 += m2 * mx;
      }
      sv0 += __shfl_xor(sv0, 16); sv0 += __shfl_xor(sv0, 32);
      sv1 += __shfl_xor(sv1, 16); sv1 += __shfl_xor(sv1, 32);
      sv2 += __shfl_xor(sv2, 16); sv2 += __shfl_xor(sv2, 32);
      if (cb == rowg) { ov0[m] = sv0 * 0.0625f; ov1[m] = sv1 * 0.0625f; ov2[m] = sv2 * 0.0625f; }
    }
  }

  // out_v (lane l owns d = l) + coord move, per m
#pragma unroll
  for (int m = 0; m < 2; ++m) {
    const int pm = p0 + m;
    const int vb = pm*192 + l*3;
    out[NPTS*128 + vb + 0] = feat_v[vb + 0] + ov0[m];
    out[NPTS*128 + vb + 1] = feat_v[vb + 1] + ov1[m];
    out[NPTS*128 + vb + 2] = feat_v[vb + 2] + ov2[m];
    const float wm = w_move[l];
    float cn0 = ov0[m] * wm, cn1 = ov1[m] * wm, cn2 = ov2[m] * wm;
#pragma unroll
    for (int off = 1; off <= 32; off <<= 1) {
      cn0 += __shfl_xor(cn0, off);
      cn1 += __shfl_xor(cn1, off);
      cn2 += __shfl_xor(cn2, off);
    }
    if (l == 0) {
      const int oc = NPTS*(128+192) + pm*3;
      out[oc+0] = coord[pm*3+0] + 1.25e-4f * cn0;
      out[oc+1] = coord[pm*3+1] + 1.25e-4f * cn1;
      out[oc+2] = coord[pm*3+2] + 1.25e-4f * cn2;
    }
  }
}

} // namespace

extern "C" void kernel_launch(void* const* d_in, const int* in_sizes, int n_in,
                              void* d_out, int out_size, void* d_ws, size_t ws_size,
                              hipStream_t stream) {
  const float* coord  = (const float*)d_in[0];
  const float* feat_s = (const float*)d_in[1];
  const float* feat_v = (const float*)d_in[2];
  // d_in[3] = mask: all-true, unused
  const float* W0     = (const float*)d_in[4];
  const float* W1     = (const float*)d_in[5];
  const float* w1     = (const float*)d_in[6];
  const float* b1     = (const float*)d_in[7];
  const float* w2     = (const float*)d_in[8];
  const float* b2     = (const float*)d_in[9];
  const float* wmove  = (const float*)d_in[10];
  float* out = (float*)d_out;

  char* ws = (char*)d_ws;
  int*   nei     = (int*)  (ws + 0);          // 524288 B (only 16 edge rows used)
  u16*   Wrep    = (u16*)  (ws + 524288);     // 8 x 146944 = 1175552 B
  float* w0last  = (float*)(ws + 1699840);    // 512 B
  float* w1last  = (float*)(ws + 1700352);    // 256 B
  u64*   packed4 = (u64*)  (ws + 1700608);    // 8192*4*8 = 262144 B

  setup_all<<<2352, 256, 0, stream>>>(coord, W0, W1, w1, w2, Wrep, w0last, w1last,
                                      nei, packed4);
  conv_mfma<<<NPTS/16, 512, 0, stream>>>(coord, feat_s, feat_v, nei, packed4, Wrep,
                                         w0last, w1last, b1, b2, wmove, out);
}